// Round 15
// baseline (749.351 us; speedup 1.0000x reference)
//
#include <hip/hip_runtime.h>

#define HW 1024
#define NIMG 32
#define IMGPX ((size_t)HW * HW)
#define NELEM (NIMG * IMGPX)

typedef float f2 __attribute__((ext_vector_type(2)));

// region 128x64 per block, ring 6 -> out 116x52
#define RING 6
#define TOX 116
#define TOY 52
#define NBX 9
#define NBY 20
#define LSTR 136    // words per slot; col c(0..127)->word c; col -1 ->130; col 128 ->131
#define SLOTS 34    // boundary rows per buffer: -1, {0,3 mod 4}x16, 64
#define BUFW (SLOTS * LSTR)

// ---- float <-> order-preserving unsigned (for atomic min/max) ----
__device__ __forceinline__ unsigned f2su(float f) {
    unsigned u = __float_as_uint(f);
    return (u & 0x80000000u) ? ~u : (u | 0x80000000u);
}
__device__ __forceinline__ float s2f(unsigned u) {
    return __uint_as_float((u & 0x80000000u) ? (u & 0x7fffffffu) : ~u);
}

__global__ void mm_init(unsigned* mm) {
    mm[0] = 0xFFFFFFFFu;
    mm[1] = 0u;
}

__global__ __launch_bounds__(256) void mm_reduce(const float4* __restrict__ x,
                                                 unsigned* mm, int n4) {
    const int tid = threadIdx.x;
    int gid = blockIdx.x * blockDim.x + tid;
    const int stride = gridDim.x * blockDim.x;
    float vmin = 3.4e38f, vmax = -3.4e38f;
    for (int i = gid; i < n4; i += stride) {
        float4 v = x[i];
        vmin = fminf(vmin, fminf(fminf(v.x, v.y), fminf(v.z, v.w)));
        vmax = fmaxf(vmax, fmaxf(fmaxf(v.x, v.y), fmaxf(v.z, v.w)));
    }
    __shared__ float smin[256];
    __shared__ float smax[256];
    smin[tid] = vmin; smax[tid] = vmax;
    __syncthreads();
    for (int s = 128; s > 0; s >>= 1) {
        if (tid < s) {
            smin[tid] = fminf(smin[tid], smin[tid + s]);
            smax[tid] = fmaxf(smax[tid], smax[tid + s]);
        }
        __syncthreads();
    }
    if (tid == 0) {
        atomicMin(&mm[0], f2su(smin[0]));
        atomicMax(&mm[1], f2su(smax[0]));
    }
}

// clamp to [-1,1] via v_med3_f32: bit-identical to fminf(fmaxf(v,-1),1) for
// all finite v (state is always finite: inputs of clip are sums of finite
// bounded terms; never NaN/inf)
__device__ __forceinline__ f2 clamp11(f2 v) {
    f2 o;
    o.x = __builtin_amdgcn_fmed3f(v.x, -1.0f, 1.0f);
    o.y = __builtin_amdgcn_fmed3f(v.y, -1.0f, 1.0f);
    return o;
}

struct RowW { f2 P[2]; float L, R; };

// 512 threads: tx 0..31 owns 4 cols (2 f2 pairs), tyg 0..15 owns 4 rows.
// BUMODE 0: compute BU locally (fallback). 1: compute + store output tile of
// BU to global (first kernel). 2: load BU from global (later kernels).
// FIRST kernels skip step 1: conv(0,A)==0 exactly -> s1 = clip(b + BU).
template <int FIRST, int LAST, int BUMODE>
__global__ __launch_bounds__(512) void fused_k(
    const float* __restrict__ x, const float* __restrict__ sin_,
    float* __restrict__ sout, float* __restrict__ bup,
    const unsigned* __restrict__ mm,
    const float* __restrict__ wAp, const float* __restrict__ wBp,
    const float* __restrict__ biasp) {
#pragma clang fp contract(off)
    __shared__ float sb[2 * BUFW];
    const int tid = threadIdx.x;
    const int tx = tid & 31;
    const int tyg = tid >> 5;          // 0..15
    const int lane = tid & 63;
    const int laneL = (lane + 63) & 63;
    const int laneR = (lane + 1) & 63;
    const int r0 = tyg << 2;
    const int c0 = tx << 2;
    const int bx = (int)blockIdx.x, by = (int)blockIdx.y;
    const int ox = bx * TOX - RING;
    const int oy = by * TOY - RING;
    const size_t img = (size_t)blockIdx.z * IMGPX;
    const bool edgeX = (bx == 0) | (bx == NBX - 1);
    const bool edgeY = (by == 0) | (by == NBY - 1);
    const bool intr = !(edgeX | edgeY);
    const bool fullc = intr && (c0 >= RING) && (c0 + 3 < RING + TOX);

    const float xmin = s2f(mm[0]);
    const float xmax = s2f(mm[1]);
    const float scale = 2.0f / (xmax - xmin);
    const float b = biasp[0];
    const f2 b2 = f2{b, b};

    float mR[4];
#pragma unroll
    for (int i = 0; i < 4; ++i) {
        const int g = oy + r0 + i;
        mR[i] = (g >= 0 && g < HW) ? 1.0f : 0.0f;
    }
    f2 mC2[2];
#pragma unroll
    for (int p = 0; p < 2; ++p) {
        const int g0 = ox + c0 + 2 * p, g1 = g0 + 1;
        mC2[p] = f2{(g0 >= 0 && g0 < HW) ? 1.0f : 0.0f,
                    (g1 >= 0 && g1 < HW) ? 1.0f : 0.0f};
    }

    auto ldSlot = [&](int wb) -> RowW {
        RowW o;
        const float4 q0 = *reinterpret_cast<const float4*>(&sb[wb + c0]);
        o.P[0] = f2{q0.x, q0.y}; o.P[1] = f2{q0.z, q0.w};
        const float fromL = __shfl(q0.w, laneL);
        const float fromR = __shfl(q0.x, laneR);
        o.L = (tx == 0) ? sb[wb + 130] : fromL;
        o.R = (tx == 31) ? sb[wb + 131] : fromR;
        return o;
    };

    float cf[9];
    // 9-term sequential row-major conv for pixel pair p in {0,1} (exact numpy order)
    auto conv9 = [&](const RowW& A, const RowW& B, const RowW& C, int p) -> f2 {
#pragma clang fp contract(off)
        f2 acc = f2{0.0f, 0.0f};
        f2 tl, tr;
        tl = f2{(p == 0) ? A.L : A.P[0].y, A.P[p].x};
        tr = f2{A.P[p].y, (p == 0) ? A.P[1].x : A.R};
        acc = acc + f2{cf[0], cf[0]} * tl;
        acc = acc + f2{cf[1], cf[1]} * A.P[p];
        acc = acc + f2{cf[2], cf[2]} * tr;
        tl = f2{(p == 0) ? B.L : B.P[0].y, B.P[p].x};
        tr = f2{B.P[p].y, (p == 0) ? B.P[1].x : B.R};
        acc = acc + f2{cf[3], cf[3]} * tl;
        acc = acc + f2{cf[4], cf[4]} * B.P[p];
        acc = acc + f2{cf[5], cf[5]} * tr;
        tl = f2{(p == 0) ? C.L : C.P[0].y, C.P[p].x};
        tr = f2{C.P[p].y, (p == 0) ? C.P[1].x : C.R};
        acc = acc + f2{cf[6], cf[6]} * tl;
        acc = acc + f2{cf[7], cf[7]} * C.P[p];
        acc = acc + f2{cf[8], cf[8]} * tr;
        return acc;
    };

    f2 bu[4][2];

    if (BUMODE != 2) {
        // ---- phase 1: xn rows -1..64 into linear slots 0..65 (both buffers) ----
        if (intr) {
            for (int k = tid; k < 66 * 130; k += 512) {
                const int si = k / 130;
                const int cc = (k - si * 130) - 1;
                const int w = (cc == -1) ? 130 : ((cc == 128) ? 131 : cc);
                const float v =
                    (x[img + (size_t)(oy + si - 1) * HW + (ox + cc)] - xmin) * scale - 1.0f;
                sb[si * LSTR + w] = v;
            }
        } else {
            for (int k = tid; k < 66 * 130; k += 512) {
                const int si = k / 130;
                const int cc = (k - si * 130) - 1;
                const int w = (cc == -1) ? 130 : ((cc == 128) ? 131 : cc);
                const int gr = oy + si - 1;
                const int gc = ox + cc;
                float v = 0.0f;
                if (gr >= 0 && gr < HW && gc >= 0 && gc < HW)
                    v = (x[img + (size_t)gr * HW + gc] - xmin) * scale - 1.0f;
                sb[si * LSTR + w] = v;
            }
        }
        __syncthreads();

        // ---- phase 2: BU = conv(xn, B) ----
#pragma unroll
        for (int i = 0; i < 9; ++i) cf[i] = wBp[i];
        {
            RowW prev = ldSlot((r0) * LSTR);
            RowW cur = ldSlot((r0 + 1) * LSTR);
#pragma unroll
            for (int i = 0; i < 4; ++i) {
                RowW nxt = ldSlot((r0 + 2 + i) * LSTR);
                bu[i][0] = conv9(prev, cur, nxt, 0);
                bu[i][1] = conv9(prev, cur, nxt, 1);
                prev = cur; cur = nxt;
            }
        }
        __syncthreads();

        if (BUMODE == 1) {
            // store output-tile portion of BU (tiles partition the image; every
            // writer computes the exact same bits -> deterministic)
#pragma unroll
            for (int i = 0; i < 4; ++i) {
                const int r = r0 + i;
                if (r < RING || r >= RING + TOY) continue;
                const int gr = oy + r;
                if (gr >= HW) continue;
                if (fullc) {
                    *reinterpret_cast<float4*>(&bup[img + (size_t)gr * HW + ox + c0]) =
                        make_float4(bu[i][0].x, bu[i][0].y, bu[i][1].x, bu[i][1].y);
                } else {
#pragma unroll
                    for (int cl = 0; cl < 4; ++cl) {
                        const int c = c0 + cl;
                        if (c < RING || c >= RING + TOX) continue;
                        const int gc = ox + c;
                        if (gc < 0 || gc >= HW) continue;
                        bup[img + (size_t)gr * HW + gc] = bu[i][cl >> 1][cl & 1];
                    }
                }
            }
        }
    } else {
        // ---- BUMODE 2: load BU from global (clamped addr; clamped values only
        // reach out-of-image cells, which are masked to zero) ----
        if (intr) {
#pragma unroll
            for (int i = 0; i < 4; ++i) {
                const float4 q = *reinterpret_cast<const float4*>(
                    &bup[img + (size_t)(oy + r0 + i) * HW + ox + c0]);
                bu[i][0] = f2{q.x, q.y};
                bu[i][1] = f2{q.z, q.w};
            }
        } else {
#pragma unroll
            for (int i = 0; i < 4; ++i) {
                int gr = oy + r0 + i;
                gr = (gr < 0) ? 0 : ((gr >= HW) ? HW - 1 : gr);
#pragma unroll
                for (int cl = 0; cl < 4; ++cl) {
                    int gc = ox + c0 + cl;
                    gc = (gc < 0) ? 0 : ((gc >= HW) ? HW - 1 : gc);
                    bu[i][cl >> 1][cl & 1] = bup[img + (size_t)gr * HW + gc];
                }
            }
        }
    }

    // ---- phase 3: stage s + frozen halos into BOTH buffers ----
    // slot map (per buffer): row -1 -> 0; row 4k -> 2k+1; row 4k+3 -> 2k+2; row 64 -> 33
    f2 res[4][2];
    float hS[4];  // tx==0: left halo col; tx==31: right halo col
    for (int k = tid; k < 324; k += 512) {
        int rr, cc;
        if (k < 260) { rr = (k < 130) ? -1 : 64; cc = (k % 130) - 1; }
        else {
            const int kk = k - 260;
            const int s = kk >> 1;            // 0..31
            rr = (s & 1) ? ((s >> 1) * 4 + 3) : ((s >> 1) * 4);
            cc = (kk & 1) ? 128 : -1;
        }
        const int w = (cc == -1) ? 130 : ((cc == 128) ? 131 : cc);
        const int slot = (rr == -1) ? 0 : ((rr == 64) ? 33 : ((rr >> 2) * 2 + 1 + (((rr & 3) == 3) ? 1 : 0)));
        float v = 0.0f;
        if (!FIRST) {
            const int gr = oy + rr, gc = ox + cc;
            if (gr >= 0 && gr < HW && gc >= 0 && gc < HW)
                v = sin_[img + (size_t)gr * HW + gc];
        }
        const int wo = slot * LSTR + w;
        sb[wo] = v;
        sb[BUFW + wo] = v;
    }
    if (FIRST) {
        // skip step 1: conv(s0,A) == 0 exactly and (0+b) == b bitwise, so
        // s1 = clip(b + BU) (then zero-masked outside image, as reference pad)
#pragma unroll
        for (int i = 0; i < 4; ++i) {
            hS[i] = 0.0f;  // frozen halo keeps s0 = 0 (stale-by-design, ring absorbs)
#pragma unroll
            for (int p = 0; p < 2; ++p) {
                f2 v = clamp11(b2 + bu[i][p]);
                if (edgeY) v = v * f2{mR[i], mR[i]};
                if (edgeX) v = v * mC2[p];
                res[i][p] = v;
            }
        }
    } else if (intr) {
#pragma unroll
        for (int i = 0; i < 4; ++i) {
            const float2* src = reinterpret_cast<const float2*>(
                &sin_[img + (size_t)(oy + r0 + i) * HW + ox + c0]);
            const float2 t0 = src[0];
            const float2 t1 = src[1];
            res[i][0] = f2{t0.x, t0.y};
            res[i][1] = f2{t1.x, t1.y};
            float hv = 0.0f;
            if (tx == 0) hv = sin_[img + (size_t)(oy + r0 + i) * HW + (ox - 1)];
            else if (tx == 31) hv = sin_[img + (size_t)(oy + r0 + i) * HW + (ox + 128)];
            hS[i] = hv;
        }
    } else {
#pragma unroll
        for (int i = 0; i < 4; ++i) {
            const int gr = oy + r0 + i;
            const bool rin = (gr >= 0) & (gr < HW);
#pragma unroll
            for (int cl = 0; cl < 4; ++cl) {
                const int gc = ox + c0 + cl;
                float v = 0.0f;
                if (rin && gc >= 0 && gc < HW) v = sin_[img + (size_t)gr * HW + gc];
                res[i][cl >> 1][cl & 1] = v;
            }
            float hv = 0.0f;
            if (tx == 0) {
                const int gc = ox - 1;
                if (rin && gc >= 0) hv = sin_[img + (size_t)gr * HW + gc];
            } else if (tx == 31) {
                const int gc = ox + 128;
                if (rin && gc < HW) hv = sin_[img + (size_t)gr * HW + gc];
            }
            hS[i] = hv;
        }
    }

    auto wrRow = [&](int bo, int i, int slot) {
        *reinterpret_cast<float4*>(&sb[bo + slot * LSTR + c0]) =
            make_float4(res[i][0].x, res[i][0].y, res[i][1].x, res[i][1].y);
    };
    wrRow(0, 0, 2 * tyg + 1);
    wrRow(0, 3, 2 * tyg + 2);
    __syncthreads();

    // ---- phase 4: fused steps; split-barrier + prefetch-in-shadow ----
#pragma unroll
    for (int i = 0; i < 9; ++i) cf[i] = wAp[i];

    auto buildRow = [&](const f2 pr[2], float hs) -> RowW {
        RowW o;
        o.P[0] = pr[0]; o.P[1] = pr[1];
        const float fromL = __shfl(pr[1].y, laneL);
        const float fromR = __shfl(pr[0].x, laneR);
        o.L = (tx == 0) ? hs : fromL;
        o.R = (tx == 31) ? hs : fromR;
        return o;
    };

    auto stepRow = [&](int i, const RowW& A, const RowW& B, const RowW& C) {
        f2 n0 = conv9(A, B, C, 0);
        f2 n1 = conv9(A, B, C, 1);
        n0 = clamp11((n0 + b2) + bu[i][0]);
        n1 = clamp11((n1 + b2) + bu[i][1]);
        if (edgeY) {
            n0 = n0 * f2{mR[i], mR[i]};
            n1 = n1 * f2{mR[i], mR[i]};
        }
        if (edgeX) {
            n0 = n0 * mC2[0];
            n1 = n1 * mC2[1];
        }
        res[i][0] = n0; res[i][1] = n1;
    };

    const int slotM1 = (tyg == 0) ? 0 : 2 * tyg;
    const int slotP4 = (tyg == 15) ? 33 : 2 * tyg + 3;
    const int NST = FIRST ? 6 : 7;

    // prologue: boundary rows for step 0 come from buffer 0
    RowW m1 = ldSlot(0 + slotM1 * LSTR);
    RowW p4 = ldSlot(0 + slotP4 * LSTR);

#pragma unroll 1
    for (int t = 0; t < NST; ++t) {
        const int wro = ((t & 1) ^ 1) * BUFW;   // write buffer (read = other)
        const RowW o0 = buildRow(res[0], hS[0]);
        const RowW o1 = buildRow(res[1], hS[1]);
        const RowW o2 = buildRow(res[2], hS[2]);
        const RowW o3 = buildRow(res[3], hS[3]);
        // boundary rows first, then publish + barrier
        stepRow(0, m1, o0, o1);
        stepRow(3, o2, o3, p4);
        wrRow(wro, 0, 2 * tyg + 1);
        wrRow(wro, 3, 2 * tyg + 2);
        __syncthreads();
        // prefetch next step's boundary rows (from buffer just written),
        // latency hidden under the interior-row compute below
        if (t + 1 < NST) {
            m1 = ldSlot(wro + slotM1 * LSTR);
            p4 = ldSlot(wro + slotP4 * LSTR);
        }
        // interior rows in the barrier shadow
        stepRow(1, o0, o1, o2);
        stepRow(2, o1, o2, o3);
    }

    // ---- phase 5: store inner 116x52 tile ----
#pragma unroll
    for (int i = 0; i < 4; ++i) {
        const int r = r0 + i;
        if (r < RING || r >= RING + TOY) continue;
        const int gr = oy + r;
        if (gr >= HW) continue;  // gr >= 0 guaranteed (oy >= -6, r >= 6)
        if (fullc) {
            float2* dst = reinterpret_cast<float2*>(&sout[img + (size_t)gr * HW + ox + c0]);
            f2 v0 = res[i][0], v1 = res[i][1];
            if (LAST) {
                v0 = (v0 + f2{1.0f, 1.0f}) * f2{0.5f, 0.5f};
                v1 = (v1 + f2{1.0f, 1.0f}) * f2{0.5f, 0.5f};
            }
            dst[0] = make_float2(v0.x, v0.y);
            dst[1] = make_float2(v1.x, v1.y);
        } else {
#pragma unroll
            for (int cl = 0; cl < 4; ++cl) {
                const int c = c0 + cl;
                if (c < RING || c >= RING + TOX) continue;
                const int gc = ox + c;
                if (gc < 0 || gc >= HW) continue;
                float v = res[i][cl >> 1][cl & 1];
                if (LAST) v = (v + 1.0f) * 0.5f;
                sout[img + (size_t)gr * HW + gc] = v;
            }
        }
    }
}

extern "C" void kernel_launch(void* const* d_in, const int* in_sizes, int n_in,
                              void* d_out, int out_size, void* d_ws, size_t ws_size,
                              hipStream_t stream) {
    const float* x = (const float*)d_in[0];
    const float* wA = (const float*)d_in[1];
    const float* wB = (const float*)d_in[2];
    const float* bias = (const float*)d_in[3];
    float* out = (float*)d_out;
    unsigned* mm = (unsigned*)d_ws;
    float* pong = (float*)((char*)d_ws + 1024);  // 128 MiB s ping buffer
    float* bub = pong + NELEM;                   // 128 MiB BU buffer (if it fits)

    mm_init<<<1, 1, 0, stream>>>(mm);
    mm_reduce<<<2048, 256, 0, stream>>>((const float4*)x, mm, (int)(NELEM / 4));

    dim3 grid(NBX, NBY, NIMG);
    const size_t needBU = 1024 + 2ull * NELEM * sizeof(float);
    if (ws_size >= needBU) {
        // k1 computes+stores BU, skips step 1; k2/k3 load BU (no staging)
        fused_k<1, 0, 1><<<grid, 512, 0, stream>>>(x, nullptr, out, bub, mm, wA, wB, bias);
        fused_k<0, 0, 2><<<grid, 512, 0, stream>>>(x, out, pong, bub, mm, wA, wB, bias);
        fused_k<0, 1, 2><<<grid, 512, 0, stream>>>(x, pong, out, bub, mm, wA, wB, bias);
    } else {
        // fallback: every kernel computes its own BU (r13 scheme + skip step 1)
        fused_k<1, 0, 0><<<grid, 512, 0, stream>>>(x, nullptr, out, nullptr, mm, wA, wB, bias);
        fused_k<0, 0, 0><<<grid, 512, 0, stream>>>(x, out, pong, nullptr, mm, wA, wB, bias);
        fused_k<0, 1, 0><<<grid, 512, 0, stream>>>(x, pong, out, nullptr, mm, wA, wB, bias);
    }
}

// Round 16
// 696.105 us; speedup vs baseline: 1.0765x; 1.0765x over previous
//
#include <hip/hip_runtime.h>

#define HW 1024
#define NIMG 32
#define IMGPX ((size_t)HW * HW)
#define NELEM (NIMG * IMGPX)

typedef float f2 __attribute__((ext_vector_type(2)));

// region 128x64 per block, ring 6 -> out 116x52
#define RING 6
#define TOX 116
#define TOY 52
#define NBX 9
#define NBY 20
#define LSTR 136    // words per slot; col c(0..127)->word c; col -1 ->130; col 128 ->131
#define SLOTS 34    // boundary rows per buffer: -1, {0,3 mod 4}x16, 64
#define BUFW (SLOTS * LSTR)

// ---- float <-> order-preserving unsigned (for atomic min/max) ----
__device__ __forceinline__ unsigned f2su(float f) {
    unsigned u = __float_as_uint(f);
    return (u & 0x80000000u) ? ~u : (u | 0x80000000u);
}
__device__ __forceinline__ float s2f(unsigned u) {
    return __uint_as_float((u & 0x80000000u) ? (u & 0x7fffffffu) : ~u);
}

__global__ void mm_init(unsigned* mm) {
    mm[0] = 0xFFFFFFFFu;
    mm[1] = 0u;
}

__global__ __launch_bounds__(256) void mm_reduce(const float4* __restrict__ x,
                                                 unsigned* mm, int n4) {
    const int tid = threadIdx.x;
    int gid = blockIdx.x * blockDim.x + tid;
    const int stride = gridDim.x * blockDim.x;
    float vmin = 3.4e38f, vmax = -3.4e38f;
    for (int i = gid; i < n4; i += stride) {
        float4 v = x[i];
        vmin = fminf(vmin, fminf(fminf(v.x, v.y), fminf(v.z, v.w)));
        vmax = fmaxf(vmax, fmaxf(fmaxf(v.x, v.y), fmaxf(v.z, v.w)));
    }
    __shared__ float smin[256];
    __shared__ float smax[256];
    smin[tid] = vmin; smax[tid] = vmax;
    __syncthreads();
    for (int s = 128; s > 0; s >>= 1) {
        if (tid < s) {
            smin[tid] = fminf(smin[tid], smin[tid + s]);
            smax[tid] = fmaxf(smax[tid], smax[tid + s]);
        }
        __syncthreads();
    }
    if (tid == 0) {
        atomicMin(&mm[0], f2su(smin[0]));
        atomicMax(&mm[1], f2su(smax[0]));
    }
}

struct RowW { f2 P[2]; float L, R; };

// 512 threads: tx 0..31 owns 4 cols (2 f2 pairs), tyg 0..15 owns 4 rows.
// BUMODE 0: compute BU locally (fallback). 1: compute + store output tile of
// BU to global (first kernel). 2: load BU from global (later kernels).
// FIRST kernels skip step 1: conv(0,A)==0 exactly -> s1 = clip(b + BU).
template <int FIRST, int LAST, int BUMODE>
__global__ __launch_bounds__(512) void fused_k(
    const float* __restrict__ x, const float* __restrict__ sin_,
    float* __restrict__ sout, float* __restrict__ bup,
    const unsigned* __restrict__ mm,
    const float* __restrict__ wAp, const float* __restrict__ wBp,
    const float* __restrict__ biasp) {
#pragma clang fp contract(off)
    __shared__ float sb[2 * BUFW];
    const int tid = threadIdx.x;
    const int tx = tid & 31;
    const int tyg = tid >> 5;          // 0..15
    const int lane = tid & 63;
    const int laneL = (lane + 63) & 63;
    const int laneR = (lane + 1) & 63;
    const int r0 = tyg << 2;
    const int c0 = tx << 2;
    const int bx = (int)blockIdx.x, by = (int)blockIdx.y;
    const int ox = bx * TOX - RING;
    const int oy = by * TOY - RING;
    const size_t img = (size_t)blockIdx.z * IMGPX;
    const bool edgeX = (bx == 0) | (bx == NBX - 1);
    const bool edgeY = (by == 0) | (by == NBY - 1);
    const bool intr = !(edgeX | edgeY);
    const bool fullc = intr && (c0 >= RING) && (c0 + 3 < RING + TOX);

    const float xmin = s2f(mm[0]);
    const float xmax = s2f(mm[1]);
    const float scale = 2.0f / (xmax - xmin);
    const float b = biasp[0];
    const f2 b2 = f2{b, b};

    float mR[4];
#pragma unroll
    for (int i = 0; i < 4; ++i) {
        const int g = oy + r0 + i;
        mR[i] = (g >= 0 && g < HW) ? 1.0f : 0.0f;
    }
    f2 mC2[2];
#pragma unroll
    for (int p = 0; p < 2; ++p) {
        const int g0 = ox + c0 + 2 * p, g1 = g0 + 1;
        mC2[p] = f2{(g0 >= 0 && g0 < HW) ? 1.0f : 0.0f,
                    (g1 >= 0 && g1 < HW) ? 1.0f : 0.0f};
    }

    auto ldSlot = [&](int wb) -> RowW {
        RowW o;
        const float4 q0 = *reinterpret_cast<const float4*>(&sb[wb + c0]);
        o.P[0] = f2{q0.x, q0.y}; o.P[1] = f2{q0.z, q0.w};
        const float fromL = __shfl(q0.w, laneL);
        const float fromR = __shfl(q0.x, laneR);
        o.L = (tx == 0) ? sb[wb + 130] : fromL;
        o.R = (tx == 31) ? sb[wb + 131] : fromR;
        return o;
    };

    float cf[9];
    // 9-term sequential row-major conv for pixel pair p in {0,1} (exact numpy order)
    auto conv9 = [&](const RowW& A, const RowW& B, const RowW& C, int p) -> f2 {
#pragma clang fp contract(off)
        f2 acc = f2{0.0f, 0.0f};
        f2 tl, tr;
        tl = f2{(p == 0) ? A.L : A.P[0].y, A.P[p].x};
        tr = f2{A.P[p].y, (p == 0) ? A.P[1].x : A.R};
        acc = acc + f2{cf[0], cf[0]} * tl;
        acc = acc + f2{cf[1], cf[1]} * A.P[p];
        acc = acc + f2{cf[2], cf[2]} * tr;
        tl = f2{(p == 0) ? B.L : B.P[0].y, B.P[p].x};
        tr = f2{B.P[p].y, (p == 0) ? B.P[1].x : B.R};
        acc = acc + f2{cf[3], cf[3]} * tl;
        acc = acc + f2{cf[4], cf[4]} * B.P[p];
        acc = acc + f2{cf[5], cf[5]} * tr;
        tl = f2{(p == 0) ? C.L : C.P[0].y, C.P[p].x};
        tr = f2{C.P[p].y, (p == 0) ? C.P[1].x : C.R};
        acc = acc + f2{cf[6], cf[6]} * tl;
        acc = acc + f2{cf[7], cf[7]} * C.P[p];
        acc = acc + f2{cf[8], cf[8]} * tr;
        return acc;
    };

    f2 bu[4][2];

    if (BUMODE != 2) {
        // ---- phase 1: xn rows -1..64 into linear slots 0..65 (both buffers) ----
        if (intr) {
            for (int k = tid; k < 66 * 130; k += 512) {
                const int si = k / 130;
                const int cc = (k - si * 130) - 1;
                const int w = (cc == -1) ? 130 : ((cc == 128) ? 131 : cc);
                const float v =
                    (x[img + (size_t)(oy + si - 1) * HW + (ox + cc)] - xmin) * scale - 1.0f;
                sb[si * LSTR + w] = v;
            }
        } else {
            for (int k = tid; k < 66 * 130; k += 512) {
                const int si = k / 130;
                const int cc = (k - si * 130) - 1;
                const int w = (cc == -1) ? 130 : ((cc == 128) ? 131 : cc);
                const int gr = oy + si - 1;
                const int gc = ox + cc;
                float v = 0.0f;
                if (gr >= 0 && gr < HW && gc >= 0 && gc < HW)
                    v = (x[img + (size_t)gr * HW + gc] - xmin) * scale - 1.0f;
                sb[si * LSTR + w] = v;
            }
        }
        __syncthreads();

        // ---- phase 2: BU = conv(xn, B) ----
#pragma unroll
        for (int i = 0; i < 9; ++i) cf[i] = wBp[i];
        {
            RowW prev = ldSlot((r0) * LSTR);
            RowW cur = ldSlot((r0 + 1) * LSTR);
#pragma unroll
            for (int i = 0; i < 4; ++i) {
                RowW nxt = ldSlot((r0 + 2 + i) * LSTR);
                bu[i][0] = conv9(prev, cur, nxt, 0);
                bu[i][1] = conv9(prev, cur, nxt, 1);
                prev = cur; cur = nxt;
            }
        }
        __syncthreads();

        if (BUMODE == 1) {
            // store output-tile portion of BU (tiles partition the image; every
            // writer computes the exact same bits -> deterministic)
#pragma unroll
            for (int i = 0; i < 4; ++i) {
                const int r = r0 + i;
                if (r < RING || r >= RING + TOY) continue;
                const int gr = oy + r;
                if (gr >= HW) continue;
                if (fullc) {
                    *reinterpret_cast<float4*>(&bup[img + (size_t)gr * HW + ox + c0]) =
                        make_float4(bu[i][0].x, bu[i][0].y, bu[i][1].x, bu[i][1].y);
                } else {
#pragma unroll
                    for (int cl = 0; cl < 4; ++cl) {
                        const int c = c0 + cl;
                        if (c < RING || c >= RING + TOX) continue;
                        const int gc = ox + c;
                        if (gc < 0 || gc >= HW) continue;
                        bup[img + (size_t)gr * HW + gc] = bu[i][cl >> 1][cl & 1];
                    }
                }
            }
        }
    } else {
        // ---- BUMODE 2: load BU from global (clamped addr; clamped values only
        // reach out-of-image cells, which are masked to zero) ----
        if (intr) {
#pragma unroll
            for (int i = 0; i < 4; ++i) {
                const float4 q = *reinterpret_cast<const float4*>(
                    &bup[img + (size_t)(oy + r0 + i) * HW + ox + c0]);
                bu[i][0] = f2{q.x, q.y};
                bu[i][1] = f2{q.z, q.w};
            }
        } else {
#pragma unroll
            for (int i = 0; i < 4; ++i) {
                int gr = oy + r0 + i;
                gr = (gr < 0) ? 0 : ((gr >= HW) ? HW - 1 : gr);
#pragma unroll
                for (int cl = 0; cl < 4; ++cl) {
                    int gc = ox + c0 + cl;
                    gc = (gc < 0) ? 0 : ((gc >= HW) ? HW - 1 : gc);
                    bu[i][cl >> 1][cl & 1] = bup[img + (size_t)gr * HW + gc];
                }
            }
        }
    }

    // ---- phase 3: stage s + frozen halos into BOTH buffers ----
    // slot map (per buffer): row -1 -> 0; row 4k -> 2k+1; row 4k+3 -> 2k+2; row 64 -> 33
    f2 res[4][2];
    float hS[4];  // tx==0: left halo col; tx==31: right halo col
    for (int k = tid; k < 324; k += 512) {
        int rr, cc;
        if (k < 260) { rr = (k < 130) ? -1 : 64; cc = (k % 130) - 1; }
        else {
            const int kk = k - 260;
            const int s = kk >> 1;            // 0..31
            rr = (s & 1) ? ((s >> 1) * 4 + 3) : ((s >> 1) * 4);
            cc = (kk & 1) ? 128 : -1;
        }
        const int w = (cc == -1) ? 130 : ((cc == 128) ? 131 : cc);
        const int slot = (rr == -1) ? 0 : ((rr == 64) ? 33 : ((rr >> 2) * 2 + 1 + (((rr & 3) == 3) ? 1 : 0)));
        float v = 0.0f;
        if (!FIRST) {
            const int gr = oy + rr, gc = ox + cc;
            if (gr >= 0 && gr < HW && gc >= 0 && gc < HW)
                v = sin_[img + (size_t)gr * HW + gc];
        }
        const int wo = slot * LSTR + w;
        sb[wo] = v;
        sb[BUFW + wo] = v;
    }
    if (FIRST) {
        // skip step 1: conv(s0,A) == 0 exactly and (0+b) == b bitwise, so
        // s1 = clip(b + BU) (then zero-masked outside image, as reference pad)
#pragma unroll
        for (int i = 0; i < 4; ++i) {
            hS[i] = 0.0f;  // frozen halo keeps s0 = 0 (stale-by-design, ring absorbs)
#pragma unroll
            for (int p = 0; p < 2; ++p) {
                f2 v = b2 + bu[i][p];
                v = __builtin_elementwise_max(v, f2{-1.0f, -1.0f});
                v = __builtin_elementwise_min(v, f2{1.0f, 1.0f});
                if (!intr) {
                    v = v * f2{mR[i], mR[i]};
                    v = v * mC2[p];
                }
                res[i][p] = v;
            }
        }
    } else if (intr) {
#pragma unroll
        for (int i = 0; i < 4; ++i) {
            const float2* src = reinterpret_cast<const float2*>(
                &sin_[img + (size_t)(oy + r0 + i) * HW + ox + c0]);
            const float2 t0 = src[0];
            const float2 t1 = src[1];
            res[i][0] = f2{t0.x, t0.y};
            res[i][1] = f2{t1.x, t1.y};
            float hv = 0.0f;
            if (tx == 0) hv = sin_[img + (size_t)(oy + r0 + i) * HW + (ox - 1)];
            else if (tx == 31) hv = sin_[img + (size_t)(oy + r0 + i) * HW + (ox + 128)];
            hS[i] = hv;
        }
    } else {
#pragma unroll
        for (int i = 0; i < 4; ++i) {
            const int gr = oy + r0 + i;
            const bool rin = (gr >= 0) & (gr < HW);
#pragma unroll
            for (int cl = 0; cl < 4; ++cl) {
                const int gc = ox + c0 + cl;
                float v = 0.0f;
                if (rin && gc >= 0 && gc < HW) v = sin_[img + (size_t)gr * HW + gc];
                res[i][cl >> 1][cl & 1] = v;
            }
            float hv = 0.0f;
            if (tx == 0) {
                const int gc = ox - 1;
                if (rin && gc >= 0) hv = sin_[img + (size_t)gr * HW + gc];
            } else if (tx == 31) {
                const int gc = ox + 128;
                if (rin && gc < HW) hv = sin_[img + (size_t)gr * HW + gc];
            }
            hS[i] = hv;
        }
    }

    auto wrRow = [&](int bo, int i, int slot) {
        *reinterpret_cast<float4*>(&sb[bo + slot * LSTR + c0]) =
            make_float4(res[i][0].x, res[i][0].y, res[i][1].x, res[i][1].y);
    };
    wrRow(0, 0, 2 * tyg + 1);
    wrRow(0, 3, 2 * tyg + 2);
    __syncthreads();

    // ---- phase 4: fused steps, split-barrier schedule ----
#pragma unroll
    for (int i = 0; i < 9; ++i) cf[i] = wAp[i];

    auto buildRow = [&](const f2 pr[2], float hs) -> RowW {
        RowW o;
        o.P[0] = pr[0]; o.P[1] = pr[1];
        const float fromL = __shfl(pr[1].y, laneL);
        const float fromR = __shfl(pr[0].x, laneR);
        o.L = (tx == 0) ? hs : fromL;
        o.R = (tx == 31) ? hs : fromR;
        return o;
    };

    auto stepRow = [&](int i, const RowW& A, const RowW& B, const RowW& C) {
        f2 n0 = conv9(A, B, C, 0);
        f2 n1 = conv9(A, B, C, 1);
        n0 = (n0 + b2) + bu[i][0];
        n1 = (n1 + b2) + bu[i][1];
        n0 = __builtin_elementwise_max(n0, f2{-1.0f, -1.0f});
        n0 = __builtin_elementwise_min(n0, f2{1.0f, 1.0f});
        n1 = __builtin_elementwise_max(n1, f2{-1.0f, -1.0f});
        n1 = __builtin_elementwise_min(n1, f2{1.0f, 1.0f});
        if (!intr) {
            n0 = n0 * f2{mR[i], mR[i]};
            n1 = n1 * f2{mR[i], mR[i]};
            n0 = n0 * mC2[0];
            n1 = n1 * mC2[1];
        }
        res[i][0] = n0; res[i][1] = n1;
    };

    const int slotM1 = (tyg == 0) ? 0 : 2 * tyg;
    const int slotP4 = (tyg == 15) ? 33 : 2 * tyg + 3;
    const int NST = FIRST ? 6 : 7;

#pragma unroll 1
    for (int t = 0; t < NST; ++t) {
        const int rdo = (t & 1) * BUFW;
        const int wro = BUFW - rdo;
        const RowW m1 = ldSlot(rdo + slotM1 * LSTR);   // old row r0-1
        const RowW p4 = ldSlot(rdo + slotP4 * LSTR);   // old row r0+4
        const RowW o0 = buildRow(res[0], hS[0]);
        const RowW o1 = buildRow(res[1], hS[1]);
        const RowW o2 = buildRow(res[2], hS[2]);
        const RowW o3 = buildRow(res[3], hS[3]);
        // boundary rows first, then publish + barrier
        stepRow(0, m1, o0, o1);
        stepRow(3, o2, o3, p4);
        wrRow(wro, 0, 2 * tyg + 1);
        wrRow(wro, 3, 2 * tyg + 2);
        __syncthreads();
        // interior rows in the barrier shadow
        stepRow(1, o0, o1, o2);
        stepRow(2, o1, o2, o3);
    }

    // ---- phase 5: store inner 116x52 tile ----
#pragma unroll
    for (int i = 0; i < 4; ++i) {
        const int r = r0 + i;
        if (r < RING || r >= RING + TOY) continue;
        const int gr = oy + r;
        if (gr >= HW) continue;  // gr >= 0 guaranteed (oy >= -6, r >= 6)
        if (fullc) {
            float2* dst = reinterpret_cast<float2*>(&sout[img + (size_t)gr * HW + ox + c0]);
            f2 v0 = res[i][0], v1 = res[i][1];
            if (LAST) {
                v0 = (v0 + f2{1.0f, 1.0f}) * f2{0.5f, 0.5f};
                v1 = (v1 + f2{1.0f, 1.0f}) * f2{0.5f, 0.5f};
            }
            dst[0] = make_float2(v0.x, v0.y);
            dst[1] = make_float2(v1.x, v1.y);
        } else {
#pragma unroll
            for (int cl = 0; cl < 4; ++cl) {
                const int c = c0 + cl;
                if (c < RING || c >= RING + TOX) continue;
                const int gc = ox + c;
                if (gc < 0 || gc >= HW) continue;
                float v = res[i][cl >> 1][cl & 1];
                if (LAST) v = (v + 1.0f) * 0.5f;
                sout[img + (size_t)gr * HW + gc] = v;
            }
        }
    }
}

extern "C" void kernel_launch(void* const* d_in, const int* in_sizes, int n_in,
                              void* d_out, int out_size, void* d_ws, size_t ws_size,
                              hipStream_t stream) {
    const float* x = (const float*)d_in[0];
    const float* wA = (const float*)d_in[1];
    const float* wB = (const float*)d_in[2];
    const float* bias = (const float*)d_in[3];
    float* out = (float*)d_out;
    unsigned* mm = (unsigned*)d_ws;
    float* pong = (float*)((char*)d_ws + 1024);  // 128 MiB s ping buffer
    float* bub = pong + NELEM;                   // 128 MiB BU buffer (if it fits)

    mm_init<<<1, 1, 0, stream>>>(mm);
    mm_reduce<<<2048, 256, 0, stream>>>((const float4*)x, mm, (int)(NELEM / 4));

    dim3 grid(NBX, NBY, NIMG);
    const size_t needBU = 1024 + 2ull * NELEM * sizeof(float);
    if (ws_size >= needBU) {
        // k1 computes+stores BU, skips step 1; k2/k3 load BU (no staging)
        fused_k<1, 0, 1><<<grid, 512, 0, stream>>>(x, nullptr, out, bub, mm, wA, wB, bias);
        fused_k<0, 0, 2><<<grid, 512, 0, stream>>>(x, out, pong, bub, mm, wA, wB, bias);
        fused_k<0, 1, 2><<<grid, 512, 0, stream>>>(x, pong, out, bub, mm, wA, wB, bias);
    } else {
        // fallback: every kernel computes its own BU (r13 scheme + skip step 1)
        fused_k<1, 0, 0><<<grid, 512, 0, stream>>>(x, nullptr, out, nullptr, mm, wA, wB, bias);
        fused_k<0, 0, 0><<<grid, 512, 0, stream>>>(x, out, pong, nullptr, mm, wA, wB, bias);
        fused_k<0, 1, 0><<<grid, 512, 0, stream>>>(x, pong, out, nullptr, mm, wA, wB, bias);
    }
}